// Round 1
// baseline (1937.156 us; speedup 1.0000x reference)
//
#include <hip/hip_runtime.h>
#include <math.h>

#define D_MODEL 1024
#define D_INNER 2048
#define DPROJ   96      // DT_RANK + 2*D_STATE
#define DT_RANK 64
#define NSTATE  16
#define SEQ     2048
#define CL      64      // chunk length for scan
#define NCH     (SEQ/CL)

__device__ __forceinline__ float silu_f(float x) { return x / (1.f + expf(-x)); }

// res = a (+ b), xn = rmsnorm(res) * w
__global__ __launch_bounds__(256) void addrms_kernel(
    const float* __restrict__ a, const float* __restrict__ b,
    const float* __restrict__ w, float* __restrict__ res_out,
    float* __restrict__ xn_out) {
  int t = blockIdx.x;
  int tid = threadIdx.x;
  float v[4];
  float ss = 0.f;
#pragma unroll
  for (int j = 0; j < 4; ++j) {
    int dcol = tid + j * 256;
    float x = a[(size_t)t * D_MODEL + dcol];
    if (b) x += b[(size_t)t * D_MODEL + dcol];
    v[j] = x;
    ss += x * x;
  }
#pragma unroll
  for (int off = 32; off > 0; off >>= 1) ss += __shfl_down(ss, off);
  __shared__ float red[4];
  __shared__ float rmsv;
  int wid = tid >> 6, lane = tid & 63;
  if (lane == 0) red[wid] = ss;
  __syncthreads();
  if (tid == 0) {
    float s = red[0] + red[1] + red[2] + red[3];
    rmsv = rsqrtf(s / (float)D_MODEL + 1e-5f);
  }
  __syncthreads();
  float r = rmsv;
#pragma unroll
  for (int j = 0; j < 4; ++j) {
    int dcol = tid + j * 256;
    res_out[(size_t)t * D_MODEL + dcol] = v[j];
    xn_out[(size_t)t * D_MODEL + dcol] = v[j] * r * w[dcol];
  }
}

// C[m,n] = sum_k A[m,k]*B[n,k]   (both row-major, "NT")
#define BM 64
#define BN 64
#define BK 16
__global__ __launch_bounds__(256) void gemm_nt(
    const float* __restrict__ A, const float* __restrict__ B, float* __restrict__ C,
    int M, int N, int K, int lda, int ldb, int ldc) {
  __shared__ float As[BK][BM + 4];
  __shared__ float Bs[BK][BN + 4];
  int tid = threadIdx.x;
  int bm = blockIdx.y * BM;
  int bn = blockIdx.x * BN;
  int tx = tid & 15, ty = tid >> 4;
  int row_base = ty * 4, col_base = tx * 4;
  float acc[4][4] = {};
  int kk = tid & 15;
  int r0 = tid >> 4;
  for (int kt = 0; kt < K; kt += BK) {
    int gk = kt + kk;
#pragma unroll
    for (int j = 0; j < 4; ++j) {
      int r = r0 + 16 * j;
      int gr = bm + r;
      As[kk][r] = (gr < M && gk < K) ? A[(size_t)gr * lda + gk] : 0.f;
      int gc = bn + r;
      Bs[kk][r] = (gc < N && gk < K) ? B[(size_t)gc * ldb + gk] : 0.f;
    }
    __syncthreads();
#pragma unroll
    for (int k2 = 0; k2 < BK; ++k2) {
      float4 av = *(const float4*)&As[k2][row_base];
      float4 bv = *(const float4*)&Bs[k2][col_base];
      float aa[4] = {av.x, av.y, av.z, av.w};
      float bb[4] = {bv.x, bv.y, bv.z, bv.w};
#pragma unroll
      for (int i2 = 0; i2 < 4; ++i2)
#pragma unroll
        for (int j2 = 0; j2 < 4; ++j2)
          acc[i2][j2] = fmaf(aa[i2], bb[j2], acc[i2][j2]);
    }
    __syncthreads();
  }
#pragma unroll
  for (int i2 = 0; i2 < 4; ++i2) {
    int gr = bm + row_base + i2;
    if (gr >= M) continue;
#pragma unroll
    for (int j2 = 0; j2 < 4; ++j2) {
      int gc = bn + col_base + j2;
      if (gc < N) C[(size_t)gr * ldc + gc] = acc[i2][j2];
    }
  }
}

// depthwise causal conv (k=4) + silu; input is xi = xz[:, :2048] (stride 4096)
__global__ __launch_bounds__(256) void conv_silu_kernel(
    const float* __restrict__ xz, const float* __restrict__ cw,
    const float* __restrict__ cb, float* __restrict__ xc) {
  int idx = blockIdx.x * 256 + threadIdx.x;
  int t = idx >> 11;
  int c = idx & 2047;
  float acc = cb[c];
  float w0 = cw[c * 4 + 0], w1 = cw[c * 4 + 1], w2 = cw[c * 4 + 2], w3 = cw[c * 4 + 3];
  if (t >= 3) acc += xz[(size_t)(t - 3) * 4096 + c] * w0;
  if (t >= 2) acc += xz[(size_t)(t - 2) * 4096 + c] * w1;
  if (t >= 1) acc += xz[(size_t)(t - 1) * 4096 + c] * w2;
  acc += xz[(size_t)t * 4096 + c] * w3;
  xc[idx] = silu_f(acc);
}

__global__ __launch_bounds__(256) void dt_softplus_kernel(
    float* __restrict__ dtb, const float* __restrict__ bias) {
  int idx = blockIdx.x * 256 + threadIdx.x;
  int d = idx & 2047;
  float x = dtb[idx] + bias[d];
  dtb[idx] = fmaxf(x, 0.f) + log1pf(expf(-fabsf(x)));
}

// Pass A: per-chunk cumulative dA product + local end state (h0 = 0)
__global__ __launch_bounds__(256) void scan_passA_kernel(
    const float* __restrict__ dtb, const float* __restrict__ xc,
    const float* __restrict__ dbc, const float* __restrict__ A_log,
    float* __restrict__ aprod, float* __restrict__ hend) {
  int c = blockIdx.x;
  int d = blockIdx.y * 256 + threadIdx.x;
  float Av[NSTATE], h[NSTATE], ap[NSTATE];
#pragma unroll
  for (int n = 0; n < NSTATE; ++n) {
    Av[n] = -expf(A_log[(size_t)d * NSTATE + n]);
    h[n] = 0.f;
    ap[n] = 1.f;
  }
  int t0 = c * CL;
  for (int tt = 0; tt < CL; ++tt) {
    int t = t0 + tt;
    float dtv = dtb[(size_t)t * D_INNER + d];
    float uv  = xc[(size_t)t * D_INNER + d];
    float du = dtv * uv;
    const float* Brow = &dbc[(size_t)t * DPROJ + DT_RANK];
#pragma unroll
    for (int n = 0; n < NSTATE; ++n) {
      float dA = expf(dtv * Av[n]);
      h[n] = fmaf(dA, h[n], du * Brow[n]);
      ap[n] *= dA;
    }
  }
  size_t base = ((size_t)c * D_INNER + d) * NSTATE;
#pragma unroll
  for (int n = 0; n < NSTATE; ++n) {
    aprod[base + n] = ap[n];
    hend[base + n] = h[n];
  }
}

// Pass B: sequential carry across the 32 chunks; hin[c] = state entering chunk c
__global__ __launch_bounds__(256) void scan_passB_kernel(
    const float* __restrict__ aprod, const float* __restrict__ hend,
    float* __restrict__ hin) {
  size_t idx = (size_t)blockIdx.x * 256 + threadIdx.x;  // d*16+n
  const size_t stride = (size_t)D_INNER * NSTATE;
  float h = 0.f;
  for (int c = 0; c < NCH; ++c) {
    hin[c * stride + idx] = h;
    h = fmaf(aprod[c * stride + idx], h, hend[c * stride + idx]);
  }
}

// Pass C: exact rescan from hin; fuse y = (scan + u*D) * silu(z)
__global__ __launch_bounds__(256) void scan_passC_kernel(
    const float* __restrict__ dtb, const float* __restrict__ xc,
    const float* __restrict__ dbc, const float* __restrict__ A_log,
    const float* __restrict__ Dp, const float* __restrict__ xz,
    const float* __restrict__ hin, float* __restrict__ y) {
  int c = blockIdx.x;
  int d = blockIdx.y * 256 + threadIdx.x;
  float Av[NSTATE], h[NSTATE];
  size_t base = ((size_t)c * D_INNER + d) * NSTATE;
#pragma unroll
  for (int n = 0; n < NSTATE; ++n) {
    Av[n] = -expf(A_log[(size_t)d * NSTATE + n]);
    h[n] = hin[base + n];
  }
  float Dv = Dp[d];
  int t0 = c * CL;
  for (int tt = 0; tt < CL; ++tt) {
    int t = t0 + tt;
    float dtv = dtb[(size_t)t * D_INNER + d];
    float uv  = xc[(size_t)t * D_INNER + d];
    float du = dtv * uv;
    const float* Brow = &dbc[(size_t)t * DPROJ + DT_RANK];
    const float* Crow = &dbc[(size_t)t * DPROJ + DT_RANK + NSTATE];
    float yv = 0.f;
#pragma unroll
    for (int n = 0; n < NSTATE; ++n) {
      float dA = expf(dtv * Av[n]);
      h[n] = fmaf(dA, h[n], du * Brow[n]);
      yv = fmaf(h[n], Crow[n], yv);
    }
    float zv = xz[(size_t)t * (2 * D_INNER) + D_INNER + d];
    y[(size_t)t * D_INNER + d] = (yv + uv * Dv) * silu_f(zv);
  }
}

extern "C" void kernel_launch(void* const* d_in, const int* in_sizes, int n_in,
                              void* d_out, int out_size, void* d_ws, size_t ws_size,
                              hipStream_t stream) {
  const float* h_in   = (const float*)d_in[0];
  const float* norm_w = (const float*)d_in[1];
  const float* in_w   = (const float*)d_in[2];
  const float* conv_w = (const float*)d_in[3];
  const float* conv_b = (const float*)d_in[4];
  const float* xp_w   = (const float*)d_in[5];
  const float* dt_w   = (const float*)d_in[6];
  const float* dt_b   = (const float*)d_in[7];
  const float* A_log  = (const float*)d_in[8];
  const float* Dp     = (const float*)d_in[9];
  const float* out_w  = (const float*)d_in[10];
  const float* normf  = (const float*)d_in[11];
  float* out = (float*)d_out;

  float* ws = (float*)d_ws;
  const size_t TD = (size_t)SEQ * D_MODEL;   // 2M floats
  const size_t TI = (size_t)SEQ * D_INNER;   // 4M floats
  const size_t ST = (size_t)NCH * D_INNER * NSTATE;  // 1M floats
  float* res   = ws; ws += TD;
  float* hn    = ws; ws += TD;
  float* xz    = ws; ws += 2 * TI;
  float* xc    = ws; ws += TI;
  float* dbc   = ws; ws += (size_t)SEQ * DPROJ;
  float* dtb   = ws; ws += TI;
  float* yb    = ws; ws += TI;
  float* hbuf  = ws; ws += TD;
  float* aprod = ws; ws += ST;
  float* hend  = ws; ws += ST;
  float* hin   = ws; ws += ST;

  const float* hcur = h_in;
  for (int i = 0; i < 2; ++i) {
    addrms_kernel<<<SEQ, 256, 0, stream>>>(hcur, i == 0 ? nullptr : res,
                                           norm_w + (size_t)i * D_MODEL, res, hn);
    gemm_nt<<<dim3(2 * D_INNER / BN, SEQ / BM), 256, 0, stream>>>(
        hn, in_w + (size_t)i * 2 * D_INNER * D_MODEL, xz,
        SEQ, 2 * D_INNER, D_MODEL, D_MODEL, D_MODEL, 2 * D_INNER);
    conv_silu_kernel<<<TI / 256, 256, 0, stream>>>(
        xz, conv_w + (size_t)i * D_INNER * 4, conv_b + (size_t)i * D_INNER, xc);
    gemm_nt<<<dim3((DPROJ + BN - 1) / BN, SEQ / BM), 256, 0, stream>>>(
        xc, xp_w + (size_t)i * DPROJ * D_INNER, dbc,
        SEQ, DPROJ, D_INNER, D_INNER, D_INNER, DPROJ);
    gemm_nt<<<dim3(D_INNER / BN, SEQ / BM), 256, 0, stream>>>(
        dbc, dt_w + (size_t)i * D_INNER * DT_RANK, dtb,
        SEQ, D_INNER, DT_RANK, DPROJ, DT_RANK, D_INNER);
    dt_softplus_kernel<<<TI / 256, 256, 0, stream>>>(dtb, dt_b + (size_t)i * D_INNER);
    scan_passA_kernel<<<dim3(NCH, D_INNER / 256), 256, 0, stream>>>(
        dtb, xc, dbc, A_log + (size_t)i * D_INNER * NSTATE, aprod, hend);
    scan_passB_kernel<<<(D_INNER * NSTATE) / 256, 256, 0, stream>>>(aprod, hend, hin);
    scan_passC_kernel<<<dim3(NCH, D_INNER / 256), 256, 0, stream>>>(
        dtb, xc, dbc, A_log + (size_t)i * D_INNER * NSTATE,
        Dp + (size_t)i * D_INNER, xz, hin, yb);
    gemm_nt<<<dim3(D_MODEL / BN, SEQ / BM), 256, 0, stream>>>(
        yb, out_w + (size_t)i * D_MODEL * D_INNER, hbuf,
        SEQ, D_MODEL, D_INNER, D_INNER, D_INNER, D_MODEL);
    hcur = hbuf;
  }
  addrms_kernel<<<SEQ, 256, 0, stream>>>(hbuf, res, normf, hn /*scratch*/, out);
}

// Round 2
// 891.334 us; speedup vs baseline: 2.1733x; 2.1733x over previous
//
#include <hip/hip_runtime.h>
#include <math.h>

#define D_MODEL 1024
#define D_INNER 2048
#define DPROJ   96      // DT_RANK + 2*D_STATE
#define DT_RANK 64
#define NSTATE  16
#define SEQ     2048
#define CL      64      // chunk length for scan
#define NCH     (SEQ/CL)

typedef unsigned short ushort_t;
typedef short v8s __attribute__((ext_vector_type(8)));
typedef float v4f __attribute__((ext_vector_type(4)));

__device__ __forceinline__ float silu_f(float x) { return x / (1.f + expf(-x)); }

__device__ __forceinline__ ushort_t f2bf(float f) {
  union { float f; unsigned u; } x; x.f = f;
  unsigned r = x.u + 0x7fffu + ((x.u >> 16) & 1u);  // RNE; inputs finite
  return (ushort_t)(r >> 16);
}

// res = a (+ b); xn = rmsnorm(res)*w written as f32 (xnf) and/or bf16 (xnb)
__global__ __launch_bounds__(256) void addrms_kernel(
    const float* __restrict__ a, const float* __restrict__ b,
    const float* __restrict__ w, float* __restrict__ res_out,
    float* __restrict__ xnf, ushort_t* __restrict__ xnb) {
  int t = blockIdx.x;
  int tid = threadIdx.x;
  float v[4];
  float ss = 0.f;
#pragma unroll
  for (int j = 0; j < 4; ++j) {
    int dcol = tid + j * 256;
    float x = a[(size_t)t * D_MODEL + dcol];
    if (b) x += b[(size_t)t * D_MODEL + dcol];
    v[j] = x;
    ss += x * x;
  }
#pragma unroll
  for (int off = 32; off > 0; off >>= 1) ss += __shfl_down(ss, off);
  __shared__ float red[4];
  __shared__ float rmsv;
  int wid = tid >> 6, lane = tid & 63;
  if (lane == 0) red[wid] = ss;
  __syncthreads();
  if (tid == 0) {
    float s = red[0] + red[1] + red[2] + red[3];
    rmsv = rsqrtf(s / (float)D_MODEL + 1e-5f);
  }
  __syncthreads();
  float r = rmsv;
#pragma unroll
  for (int j = 0; j < 4; ++j) {
    int dcol = tid + j * 256;
    res_out[(size_t)t * D_MODEL + dcol] = v[j];
    float xn = v[j] * r * w[dcol];
    if (xnf) xnf[(size_t)t * D_MODEL + dcol] = xn;
    if (xnb) xnb[(size_t)t * D_MODEL + dcol] = f2bf(xn);
  }
}

// ---------------- bf16 MFMA GEMM (NT): C[m,n] = sum_k A[m,k]*B[n,k] ----------------
// A: bf16 (M x K, lda), B: f32 converted on the fly (N x K, ldb), C: f32 (M x N, ldc)
// 128x128 tile, BK=32, 4 waves (2x2), each wave 64x64 = 4x4 frags of 16x16x32.
// SPLITK>1: blockIdx.z selects K-chunk, C offset by z*M*ldc (partials, no atomics).
template <int SPLITK>
__global__ __launch_bounds__(256) void gemm_bf16_mfma(
    const ushort_t* __restrict__ A, const float* __restrict__ B,
    float* __restrict__ C, int M, int N, int K, int lda, int ldb, int ldc) {
  __shared__ ushort_t As[128][40];  // +8 bf16 pad (16B) keeps rows 16B-aligned, spreads banks
  __shared__ ushort_t Bs[128][40];
  int tid = threadIdx.x;
  int bm = blockIdx.y * 128;
  int bn = blockIdx.x * 128;
  int kchunk = K / SPLITK;
  int k0 = blockIdx.z * kchunk;
  if (SPLITK > 1) C += (size_t)blockIdx.z * (size_t)M * (size_t)ldc;

  int lane = tid & 63, wid = tid >> 6;
  int wr = wid >> 1, wc = wid & 1;
  int lr = lane & 15;
  int ko = (lane >> 4) * 8;

  v4f acc[4][4] = {};

  for (int kt = k0; kt < k0 + kchunk; kt += 32) {
    // stage A: 128 rows x 32 bf16 = 8KB; 2 x 16B per thread
#pragma unroll
    for (int s = 0; s < 2; ++s) {
      int slot = tid + 256 * s;
      int row = slot >> 2, seg = slot & 3;
      int gr = bm + row;
      float4 v = make_float4(0.f, 0.f, 0.f, 0.f);
      if (gr < M) v = *(const float4*)(A + (size_t)gr * lda + kt + seg * 8);
      *(float4*)&As[row][seg * 8] = v;
    }
    // stage B: 128 rows x 32 f32 -> bf16; 4 x 16B f32 loads per thread
#pragma unroll
    for (int s = 0; s < 4; ++s) {
      int slot = tid + 256 * s;
      int row = slot >> 3, c4 = slot & 7;
      int gc = bn + row;
      float4 v = make_float4(0.f, 0.f, 0.f, 0.f);
      if (gc < N) v = *(const float4*)(B + (size_t)gc * ldb + kt + c4 * 4);
      ushort4 o;
      o.x = f2bf(v.x); o.y = f2bf(v.y); o.z = f2bf(v.z); o.w = f2bf(v.w);
      *(ushort4*)&Bs[row][c4 * 4] = o;
    }
    __syncthreads();
    v8s a[4], b[4];
#pragma unroll
    for (int m = 0; m < 4; ++m)
      a[m] = *(const v8s*)&As[wr * 64 + m * 16 + lr][ko];
#pragma unroll
    for (int n = 0; n < 4; ++n)
      b[n] = *(const v8s*)&Bs[wc * 64 + n * 16 + lr][ko];
#pragma unroll
    for (int m = 0; m < 4; ++m)
#pragma unroll
      for (int n = 0; n < 4; ++n)
        acc[m][n] = __builtin_amdgcn_mfma_f32_16x16x32_bf16(a[m], b[n], acc[m][n], 0, 0, 0);
    __syncthreads();
  }

#pragma unroll
  for (int m = 0; m < 4; ++m) {
#pragma unroll
    for (int n = 0; n < 4; ++n) {
      int gc = bn + wc * 64 + n * 16 + lr;
      if (gc >= N) continue;
      int gr0 = bm + wr * 64 + m * 16 + (lane >> 4) * 4;
#pragma unroll
      for (int j = 0; j < 4; ++j) {
        C[(size_t)(gr0 + j) * ldc + gc] = acc[m][n][j];
      }
    }
  }
}

__global__ __launch_bounds__(256) void reduce4_kernel(
    const float* __restrict__ part, float* __restrict__ out, int sz) {
  int idx = blockIdx.x * 256 + threadIdx.x;
  if (idx < sz)
    out[idx] = part[idx] + part[idx + sz] + part[idx + 2 * sz] + part[idx + 3 * sz];
}

// fp32 GEMM NT (kept for dt_proj: K=64, feeds softplus->exp)
#define BM 64
#define BN 64
#define BK 16
__global__ __launch_bounds__(256) void gemm_nt(
    const float* __restrict__ A, const float* __restrict__ B, float* __restrict__ C,
    int M, int N, int K, int lda, int ldb, int ldc) {
  __shared__ float As[BK][BM + 4];
  __shared__ float Bs[BK][BN + 4];
  int tid = threadIdx.x;
  int bm = blockIdx.y * BM;
  int bn = blockIdx.x * BN;
  int tx = tid & 15, ty = tid >> 4;
  int row_base = ty * 4, col_base = tx * 4;
  float acc[4][4] = {};
  int kk = tid & 15;
  int r0 = tid >> 4;
  for (int kt = 0; kt < K; kt += BK) {
    int gk = kt + kk;
#pragma unroll
    for (int j = 0; j < 4; ++j) {
      int r = r0 + 16 * j;
      int gr = bm + r;
      As[kk][r] = (gr < M && gk < K) ? A[(size_t)gr * lda + gk] : 0.f;
      int gc = bn + r;
      Bs[kk][r] = (gc < N && gk < K) ? B[(size_t)gc * ldb + gk] : 0.f;
    }
    __syncthreads();
#pragma unroll
    for (int k2 = 0; k2 < BK; ++k2) {
      float4 av = *(const float4*)&As[k2][row_base];
      float4 bv = *(const float4*)&Bs[k2][col_base];
      float aa[4] = {av.x, av.y, av.z, av.w};
      float bb[4] = {bv.x, bv.y, bv.z, bv.w};
#pragma unroll
      for (int i2 = 0; i2 < 4; ++i2)
#pragma unroll
        for (int j2 = 0; j2 < 4; ++j2)
          acc[i2][j2] = fmaf(aa[i2], bb[j2], acc[i2][j2]);
    }
    __syncthreads();
  }
#pragma unroll
  for (int i2 = 0; i2 < 4; ++i2) {
    int gr = bm + row_base + i2;
    if (gr >= M) continue;
#pragma unroll
    for (int j2 = 0; j2 < 4; ++j2) {
      int gc = bn + col_base + j2;
      if (gc < N) C[(size_t)gr * ldc + gc] = acc[i2][j2];
    }
  }
}

// depthwise causal conv (k=4) + silu; writes f32 (scan) and bf16 (x_proj GEMM)
__global__ __launch_bounds__(256) void conv_silu_kernel(
    const float* __restrict__ xz, const float* __restrict__ cw,
    const float* __restrict__ cb, float* __restrict__ xc,
    ushort_t* __restrict__ xcb) {
  int idx = blockIdx.x * 256 + threadIdx.x;
  int t = idx >> 11;
  int c = idx & 2047;
  float acc = cb[c];
  float w0 = cw[c * 4 + 0], w1 = cw[c * 4 + 1], w2 = cw[c * 4 + 2], w3 = cw[c * 4 + 3];
  if (t >= 3) acc += xz[(size_t)(t - 3) * 4096 + c] * w0;
  if (t >= 2) acc += xz[(size_t)(t - 2) * 4096 + c] * w1;
  if (t >= 1) acc += xz[(size_t)(t - 1) * 4096 + c] * w2;
  acc += xz[(size_t)t * 4096 + c] * w3;
  float y = silu_f(acc);
  xc[idx] = y;
  xcb[idx] = f2bf(y);
}

__global__ __launch_bounds__(256) void dt_softplus_kernel(
    float* __restrict__ dtb, const float* __restrict__ bias) {
  int idx = blockIdx.x * 256 + threadIdx.x;
  int d = idx & 2047;
  float x = dtb[idx] + bias[d];
  dtb[idx] = fmaxf(x, 0.f) + log1pf(expf(-fabsf(x)));
}

// Pass A: per-chunk cumulative dA product + local end state (h0 = 0)
__global__ __launch_bounds__(256) void scan_passA_kernel(
    const float* __restrict__ dtb, const float* __restrict__ xc,
    const float* __restrict__ dbc, const float* __restrict__ A_log,
    float* __restrict__ aprod, float* __restrict__ hend) {
  int c = blockIdx.x;
  int d = blockIdx.y * 256 + threadIdx.x;
  float Av[NSTATE], h[NSTATE], ap[NSTATE];
#pragma unroll
  for (int n = 0; n < NSTATE; ++n) {
    Av[n] = -expf(A_log[(size_t)d * NSTATE + n]);
    h[n] = 0.f;
    ap[n] = 1.f;
  }
  int t0 = c * CL;
  for (int tt = 0; tt < CL; ++tt) {
    int t = t0 + tt;
    float dtv = dtb[(size_t)t * D_INNER + d];
    float uv  = xc[(size_t)t * D_INNER + d];
    float du = dtv * uv;
    const float* Brow = &dbc[(size_t)t * DPROJ + DT_RANK];
#pragma unroll
    for (int n = 0; n < NSTATE; ++n) {
      float dA = expf(dtv * Av[n]);
      h[n] = fmaf(dA, h[n], du * Brow[n]);
      ap[n] *= dA;
    }
  }
  size_t base = ((size_t)c * D_INNER + d) * NSTATE;
#pragma unroll
  for (int n = 0; n < NSTATE; ++n) {
    aprod[base + n] = ap[n];
    hend[base + n] = h[n];
  }
}

// Pass B: sequential carry across the 32 chunks
__global__ __launch_bounds__(256) void scan_passB_kernel(
    const float* __restrict__ aprod, const float* __restrict__ hend,
    float* __restrict__ hin) {
  size_t idx = (size_t)blockIdx.x * 256 + threadIdx.x;
  const size_t stride = (size_t)D_INNER * NSTATE;
  float h = 0.f;
  for (int c = 0; c < NCH; ++c) {
    hin[c * stride + idx] = h;
    h = fmaf(aprod[c * stride + idx], h, hend[c * stride + idx]);
  }
}

// Pass C: rescan from hin; y = (scan + u*D) * silu(z), written as bf16
__global__ __launch_bounds__(256) void scan_passC_kernel(
    const float* __restrict__ dtb, const float* __restrict__ xc,
    const float* __restrict__ dbc, const float* __restrict__ A_log,
    const float* __restrict__ Dp, const float* __restrict__ xz,
    const float* __restrict__ hin, ushort_t* __restrict__ yb) {
  int c = blockIdx.x;
  int d = blockIdx.y * 256 + threadIdx.x;
  float Av[NSTATE], h[NSTATE];
  size_t base = ((size_t)c * D_INNER + d) * NSTATE;
#pragma unroll
  for (int n = 0; n < NSTATE; ++n) {
    Av[n] = -expf(A_log[(size_t)d * NSTATE + n]);
    h[n] = hin[base + n];
  }
  float Dv = Dp[d];
  int t0 = c * CL;
  for (int tt = 0; tt < CL; ++tt) {
    int t = t0 + tt;
    float dtv = dtb[(size_t)t * D_INNER + d];
    float uv  = xc[(size_t)t * D_INNER + d];
    float du = dtv * uv;
    const float* Brow = &dbc[(size_t)t * DPROJ + DT_RANK];
    const float* Crow = &dbc[(size_t)t * DPROJ + DT_RANK + NSTATE];
    float yv = 0.f;
#pragma unroll
    for (int n = 0; n < NSTATE; ++n) {
      float dA = expf(dtv * Av[n]);
      h[n] = fmaf(dA, h[n], du * Brow[n]);
      yv = fmaf(h[n], Crow[n], yv);
    }
    float zv = xz[(size_t)t * (2 * D_INNER) + D_INNER + d];
    yb[(size_t)t * D_INNER + d] = f2bf((yv + uv * Dv) * silu_f(zv));
  }
}

extern "C" void kernel_launch(void* const* d_in, const int* in_sizes, int n_in,
                              void* d_out, int out_size, void* d_ws, size_t ws_size,
                              hipStream_t stream) {
  const float* h_in   = (const float*)d_in[0];
  const float* norm_w = (const float*)d_in[1];
  const float* in_w   = (const float*)d_in[2];
  const float* conv_w = (const float*)d_in[3];
  const float* conv_b = (const float*)d_in[4];
  const float* xp_w   = (const float*)d_in[5];
  const float* dt_w   = (const float*)d_in[6];
  const float* dt_b   = (const float*)d_in[7];
  const float* A_log  = (const float*)d_in[8];
  const float* Dp     = (const float*)d_in[9];
  const float* out_w  = (const float*)d_in[10];
  const float* normf  = (const float*)d_in[11];
  float* out = (float*)d_out;

  float* ws = (float*)d_ws;
  const size_t TD = (size_t)SEQ * D_MODEL;           // 2M
  const size_t TI = (size_t)SEQ * D_INNER;           // 4M
  const size_t ST = (size_t)NCH * D_INNER * NSTATE;  // 1M
  const size_t DB = (size_t)SEQ * DPROJ;             // 196608
  float* res   = ws; ws += TD;
  float* xz    = ws; ws += 2 * TI;
  float* xc    = ws; ws += TI;
  float* dbc   = ws; ws += DB;
  float* dbcp  = ws; ws += 4 * DB;
  float* dtb   = ws; ws += TI;
  float* hbuf  = ws; ws += TD;
  float* aprod = ws; ws += ST;
  float* hend  = ws; ws += ST;
  float* hin   = ws; ws += ST;
  ushort_t* hnb = (ushort_t*)ws;          // TD ushorts = TD/2 floats
  ushort_t* xcb = hnb + TD;               // TI ushorts
  ushort_t* ybf = xcb + TI;               // TI ushorts

  const float* hcur = h_in;
  for (int i = 0; i < 2; ++i) {
    addrms_kernel<<<SEQ, 256, 0, stream>>>(hcur, i == 0 ? nullptr : res,
                                           norm_w + (size_t)i * D_MODEL, res,
                                           nullptr, hnb);
    // in_proj: [2048 x 1024] x [4096 x 1024]^T -> xz [2048 x 4096]
    gemm_bf16_mfma<1><<<dim3(2 * D_INNER / 128, SEQ / 128, 1), 256, 0, stream>>>(
        hnb, in_w + (size_t)i * 2 * D_INNER * D_MODEL, xz,
        SEQ, 2 * D_INNER, D_MODEL, D_MODEL, D_MODEL, 2 * D_INNER);
    conv_silu_kernel<<<TI / 256, 256, 0, stream>>>(
        xz, conv_w + (size_t)i * D_INNER * 4, conv_b + (size_t)i * D_INNER, xc, xcb);
    // x_proj: [2048 x 2048] x [96 x 2048]^T -> dbc [2048 x 96]; split-K=4
    gemm_bf16_mfma<4><<<dim3(1, SEQ / 128, 4), 256, 0, stream>>>(
        xcb, xp_w + (size_t)i * DPROJ * D_INNER, dbcp,
        SEQ, DPROJ, D_INNER, D_INNER, D_INNER, DPROJ);
    reduce4_kernel<<<(DB + 255) / 256, 256, 0, stream>>>(dbcp, dbc, (int)DB);
    // dt_proj (fp32): [2048 x 64](ld 96) x [2048 x 64]^T -> dtb [2048 x 2048]
    gemm_nt<<<dim3(D_INNER / BN, SEQ / BM), 256, 0, stream>>>(
        dbc, dt_w + (size_t)i * D_INNER * DT_RANK, dtb,
        SEQ, D_INNER, DT_RANK, DPROJ, DT_RANK, D_INNER);
    dt_softplus_kernel<<<TI / 256, 256, 0, stream>>>(dtb, dt_b + (size_t)i * D_INNER);
    scan_passA_kernel<<<dim3(NCH, D_INNER / 256), 256, 0, stream>>>(
        dtb, xc, dbc, A_log + (size_t)i * D_INNER * NSTATE, aprod, hend);
    scan_passB_kernel<<<(D_INNER * NSTATE) / 256, 256, 0, stream>>>(aprod, hend, hin);
    scan_passC_kernel<<<dim3(NCH, D_INNER / 256), 256, 0, stream>>>(
        dtb, xc, dbc, A_log + (size_t)i * D_INNER * NSTATE,
        Dp + (size_t)i * D_INNER, xz, hin, ybf);
    // out_proj: [2048 x 2048] x [1024 x 2048]^T -> hbuf [2048 x 1024]
    gemm_bf16_mfma<1><<<dim3(D_MODEL / 128, SEQ / 128, 1), 256, 0, stream>>>(
        ybf, out_w + (size_t)i * D_MODEL * D_INNER, hbuf,
        SEQ, D_MODEL, D_INNER, D_INNER, D_INNER, D_MODEL);
    hcur = hbuf;
  }
  addrms_kernel<<<SEQ, 256, 0, stream>>>(hbuf, res, normf, res, out, nullptr);
}

// Round 3
// 565.531 us; speedup vs baseline: 3.4254x; 1.5761x over previous
//
#include <hip/hip_runtime.h>
#include <math.h>

#define D_MODEL 1024
#define D_INNER 2048
#define DPROJ   96      // DT_RANK + 2*D_STATE
#define DT_RANK 64
#define NSTATE  16
#define SEQ     2048
#define CL      64      // chunk length for scan
#define NCH     (SEQ/CL)

typedef unsigned short ushort_t;
typedef short v8s __attribute__((ext_vector_type(8)));
typedef float v4f __attribute__((ext_vector_type(4)));
typedef __attribute__((address_space(3))) unsigned int as3_u32;
typedef __attribute__((address_space(1))) unsigned int as1_u32;

__device__ __forceinline__ float silu_f(float x) { return x / (1.f + expf(-x)); }

__device__ __forceinline__ ushort_t f2bf(float f) {
  union { float f; unsigned u; } x; x.f = f;
  unsigned r = x.u + 0x7fffu + ((x.u >> 16) & 1u);  // RNE; inputs finite
  return (ushort_t)(r >> 16);
}
__device__ __forceinline__ float bf2f(ushort_t b) {
  union { unsigned u; float f; } x; x.u = ((unsigned)b) << 16; return x.f;
}

// async global->LDS, 16B per lane; lds dest = wave-uniform base + lane*16
__device__ __forceinline__ void gl_lds16(const ushort_t* g, ushort_t* l) {
  __builtin_amdgcn_global_load_lds((const as1_u32*)g, (as3_u32*)l, 16, 0, 0);
}

// res = a (+ b); xn = rmsnorm(res)*w written as f32 (xnf) and/or bf16 (xnb)
__global__ __launch_bounds__(256) void addrms_kernel(
    const float* __restrict__ a, const float* __restrict__ b,
    const float* __restrict__ w, float* __restrict__ res_out,
    float* __restrict__ xnf, ushort_t* __restrict__ xnb) {
  int t = blockIdx.x;
  int tid = threadIdx.x;
  float v[4];
  float ss = 0.f;
#pragma unroll
  for (int j = 0; j < 4; ++j) {
    int dcol = tid + j * 256;
    float x = a[(size_t)t * D_MODEL + dcol];
    if (b) x += b[(size_t)t * D_MODEL + dcol];
    v[j] = x;
    ss += x * x;
  }
#pragma unroll
  for (int off = 32; off > 0; off >>= 1) ss += __shfl_down(ss, off);
  __shared__ float red[4];
  __shared__ float rmsv;
  int wid = tid >> 6, lane = tid & 63;
  if (lane == 0) red[wid] = ss;
  __syncthreads();
  if (tid == 0) {
    float s = red[0] + red[1] + red[2] + red[3];
    rmsv = rsqrtf(s / (float)D_MODEL + 1e-5f);
  }
  __syncthreads();
  float r = rmsv;
#pragma unroll
  for (int j = 0; j < 4; ++j) {
    int dcol = tid + j * 256;
    res_out[(size_t)t * D_MODEL + dcol] = v[j];
    float xn = v[j] * r * w[dcol];
    if (xnf) xnf[(size_t)t * D_MODEL + dcol] = xn;
    if (xnb) xnb[(size_t)t * D_MODEL + dcol] = f2bf(xn);
  }
}

__global__ __launch_bounds__(256) void f2bf_kernel(
    const float* __restrict__ in, ushort_t* __restrict__ out, int n4) {
  int i = blockIdx.x * 256 + threadIdx.x;
  if (i >= n4) return;
  float4 v = ((const float4*)in)[i];
  ushort4 o;
  o.x = f2bf(v.x); o.y = f2bf(v.y); o.z = f2bf(v.z); o.w = f2bf(v.w);
  ((ushort4*)out)[i] = o;
}

// ------------- bf16 MFMA GEMM (NT): C[m,n] = sum_k A[m,k]*B[n,k] -------------
// m97 structure: 128x128 tile, BK=32, linear LDS [128][32] bf16 (16B-aligned),
// global_load_lds width16 staging, 4 waves (2x2), 4x4 frags of 16x16x32 each.
// SPLITK>1: blockIdx.z takes K-chunk, C offset z*M*ldc (deterministic partials).
template <int SPLITK, bool CLAMPN>
__global__ __launch_bounds__(256) void gemm_bt(
    const ushort_t* __restrict__ A, const ushort_t* __restrict__ B,
    float* __restrict__ C, int M, int N, int K, int lda, int ldb, int ldc) {
  __shared__ ushort_t As[128 * 32];
  __shared__ ushort_t Bs[128 * 32];
  int tid = threadIdx.x;
  int bm = blockIdx.y * 128;
  int bn = blockIdx.x * 128;
  int kchunk = K / SPLITK;
  int k0 = blockIdx.z * kchunk;
  if (SPLITK > 1) C += (size_t)blockIdx.z * (size_t)M * (size_t)ldc;

  int lane = tid & 63, wid = tid >> 6;
  int wr = wid >> 1, wc = wid & 1;
  int lr = lane & 15;
  int ko = (lane >> 4) * 8;

  // staging: chunk c = s*256 + wid*64 + lane covers LDS bytes [16c,16c+16)
  // = row c>>2, ushorts [(c&3)*8 .. +8). Global col = kt + (lane&3)*8.
  int rs0 = wid * 16 + (lane >> 2);          // s=0 row within tile
  int segc = (lane & 3) * 8;

  v4f acc[4][4] = {};

  for (int kt = k0; kt < k0 + kchunk; kt += 32) {
#pragma unroll
    for (int s = 0; s < 2; ++s) {
      int r = s * 64 + rs0;
      int cc = kt + segc;
      gl_lds16(A + (size_t)(bm + r) * lda + cc, &As[s * 2048 + wid * 512]);
      int bc = bn + r;
      if (CLAMPN) bc = min(bc, N - 1);   // stay in-bounds; junk cols never stored
      gl_lds16(B + (size_t)bc * ldb + cc, &Bs[s * 2048 + wid * 512]);
    }
    __syncthreads();
    v8s a[4], b[4];
#pragma unroll
    for (int m = 0; m < 4; ++m)
      a[m] = *(const v8s*)&As[(wr * 64 + m * 16 + lr) * 32 + ko];
#pragma unroll
    for (int n = 0; n < 4; ++n)
      b[n] = *(const v8s*)&Bs[(wc * 64 + n * 16 + lr) * 32 + ko];
#pragma unroll
    for (int m = 0; m < 4; ++m)
#pragma unroll
      for (int n = 0; n < 4; ++n)
        acc[m][n] = __builtin_amdgcn_mfma_f32_16x16x32_bf16(a[m], b[n], acc[m][n], 0, 0, 0);
    __syncthreads();
  }

#pragma unroll
  for (int m = 0; m < 4; ++m) {
#pragma unroll
    for (int n = 0; n < 4; ++n) {
      int gc = bn + wc * 64 + n * 16 + lr;
      if (gc >= N) continue;
      int gr0 = bm + wr * 64 + m * 16 + (lane >> 4) * 4;
#pragma unroll
      for (int j = 0; j < 4; ++j) {
        C[(size_t)(gr0 + j) * ldc + gc] = acc[m][n][j];
      }
    }
  }
}

// out[idx] = sum_p part[idx + p*sz]; optional bf16 mirror
__global__ __launch_bounds__(256) void reduceN_kernel(
    const float* __restrict__ part, float* __restrict__ out,
    ushort_t* __restrict__ outb, int sz, int nparts) {
  int idx = blockIdx.x * 256 + threadIdx.x;
  if (idx >= sz) return;
  float s = 0.f;
  for (int p = 0; p < nparts; ++p) s += part[idx + (size_t)p * sz];
  out[idx] = s;
  if (outb) outb[idx] = f2bf(s);
}

// depthwise causal conv (k=4) + silu -> bf16
__global__ __launch_bounds__(256) void conv_silu_kernel(
    const float* __restrict__ xz, const float* __restrict__ cw,
    const float* __restrict__ cb, ushort_t* __restrict__ xcb) {
  int idx = blockIdx.x * 256 + threadIdx.x;
  int t = idx >> 11;
  int c = idx & 2047;
  float acc = cb[c];
  float w0 = cw[c * 4 + 0], w1 = cw[c * 4 + 1], w2 = cw[c * 4 + 2], w3 = cw[c * 4 + 3];
  if (t >= 3) acc += xz[(size_t)(t - 3) * 4096 + c] * w0;
  if (t >= 2) acc += xz[(size_t)(t - 2) * 4096 + c] * w1;
  if (t >= 1) acc += xz[(size_t)(t - 1) * 4096 + c] * w2;
  acc += xz[(size_t)t * 4096 + c] * w3;
  xcb[idx] = f2bf(silu_f(acc));
}

__global__ __launch_bounds__(256) void dt_softplus_kernel(
    float* __restrict__ dtb, const float* __restrict__ bias) {
  int idx = blockIdx.x * 256 + threadIdx.x;
  int d = idx & 2047;
  float x = dtb[idx] + bias[d];
  dtb[idx] = fmaxf(x, 0.f) + log1pf(expf(-fabsf(x)));
}

// Pass A: per-chunk cumulative dA product + local end state (h0 = 0)
__global__ __launch_bounds__(256) void scan_passA_kernel(
    const float* __restrict__ dtb, const ushort_t* __restrict__ xcb,
    const float* __restrict__ dbc, const float* __restrict__ A_log,
    float* __restrict__ aprod, float* __restrict__ hend) {
  int c = blockIdx.x;
  int d = blockIdx.y * 256 + threadIdx.x;
  float Av[NSTATE], h[NSTATE], ap[NSTATE];
#pragma unroll
  for (int n = 0; n < NSTATE; ++n) {
    Av[n] = -expf(A_log[(size_t)d * NSTATE + n]);
    h[n] = 0.f;
    ap[n] = 1.f;
  }
  int t0 = c * CL;
  for (int tt = 0; tt < CL; ++tt) {
    int t = t0 + tt;
    float dtv = dtb[(size_t)t * D_INNER + d];
    float uv  = bf2f(xcb[(size_t)t * D_INNER + d]);
    float du = dtv * uv;
    const float* Brow = &dbc[(size_t)t * DPROJ + DT_RANK];
#pragma unroll
    for (int n = 0; n < NSTATE; ++n) {
      float dA = expf(dtv * Av[n]);
      h[n] = fmaf(dA, h[n], du * Brow[n]);
      ap[n] *= dA;
    }
  }
  size_t base = ((size_t)c * D_INNER + d) * NSTATE;
#pragma unroll
  for (int n = 0; n < NSTATE; ++n) {
    aprod[base + n] = ap[n];
    hend[base + n] = h[n];
  }
}

// Pass B: sequential carry across the 32 chunks
__global__ __launch_bounds__(256) void scan_passB_kernel(
    const float* __restrict__ aprod, const float* __restrict__ hend,
    float* __restrict__ hin) {
  size_t idx = (size_t)blockIdx.x * 256 + threadIdx.x;
  const size_t stride = (size_t)D_INNER * NSTATE;
  float h = 0.f;
  for (int c = 0; c < NCH; ++c) {
    hin[c * stride + idx] = h;
    h = fmaf(aprod[c * stride + idx], h, hend[c * stride + idx]);
  }
}

// Pass C: rescan from hin; y = (scan + u*D) * silu(z), written as bf16
__global__ __launch_bounds__(256) void scan_passC_kernel(
    const float* __restrict__ dtb, const ushort_t* __restrict__ xcb,
    const float* __restrict__ dbc, const float* __restrict__ A_log,
    const float* __restrict__ Dp, const float* __restrict__ xz,
    const float* __restrict__ hin, ushort_t* __restrict__ yb) {
  int c = blockIdx.x;
  int d = blockIdx.y * 256 + threadIdx.x;
  float Av[NSTATE], h[NSTATE];
  size_t base = ((size_t)c * D_INNER + d) * NSTATE;
#pragma unroll
  for (int n = 0; n < NSTATE; ++n) {
    Av[n] = -expf(A_log[(size_t)d * NSTATE + n]);
    h[n] = hin[base + n];
  }
  float Dv = Dp[d];
  int t0 = c * CL;
  for (int tt = 0; tt < CL; ++tt) {
    int t = t0 + tt;
    float dtv = dtb[(size_t)t * D_INNER + d];
    float uv  = bf2f(xcb[(size_t)t * D_INNER + d]);
    float du = dtv * uv;
    const float* Brow = &dbc[(size_t)t * DPROJ + DT_RANK];
    const float* Crow = &dbc[(size_t)t * DPROJ + DT_RANK + NSTATE];
    float yv = 0.f;
#pragma unroll
    for (int n = 0; n < NSTATE; ++n) {
      float dA = expf(dtv * Av[n]);
      h[n] = fmaf(dA, h[n], du * Brow[n]);
      yv = fmaf(h[n], Crow[n], yv);
    }
    float zv = xz[(size_t)t * (2 * D_INNER) + D_INNER + d];
    yb[(size_t)t * D_INNER + d] = f2bf((yv + uv * Dv) * silu_f(zv));
  }
}

extern "C" void kernel_launch(void* const* d_in, const int* in_sizes, int n_in,
                              void* d_out, int out_size, void* d_ws, size_t ws_size,
                              hipStream_t stream) {
  const float* h_in   = (const float*)d_in[0];
  const float* norm_w = (const float*)d_in[1];
  const float* in_w   = (const float*)d_in[2];
  const float* conv_w = (const float*)d_in[3];
  const float* conv_b = (const float*)d_in[4];
  const float* xp_w   = (const float*)d_in[5];
  const float* dt_w   = (const float*)d_in[6];
  const float* dt_b   = (const float*)d_in[7];
  const float* A_log  = (const float*)d_in[8];
  const float* Dp     = (const float*)d_in[9];
  const float* out_w  = (const float*)d_in[10];
  const float* normf  = (const float*)d_in[11];
  float* out = (float*)d_out;

  float* ws = (float*)d_ws;
  const size_t TD = (size_t)SEQ * D_MODEL;           // 2M
  const size_t TI = (size_t)SEQ * D_INNER;           // 4M
  const size_t ST = (size_t)NCH * D_INNER * NSTATE;  // 1M
  const size_t DB = (size_t)SEQ * DPROJ;             // 196608
  const size_t INW = (size_t)2 * D_INNER * D_MODEL;  // 4.19M
  const size_t XPW = (size_t)DPROJ * D_INNER;        // 196608
  const size_t DTW = (size_t)D_INNER * DT_RANK;      // 131072
  const size_t OUW = (size_t)D_MODEL * D_INNER;      // 2.10M

  float* res   = ws; ws += TD;
  float* xz    = ws; ws += 2 * TI;
  float* dbc   = ws; ws += DB;
  float* dtb   = ws; ws += TI;
  float* hbuf  = ws; ws += TD;
  float* aprod = ws; ws += ST;
  float* hend  = ws; ws += ST;
  float* hin   = ws; ws += ST;
  float* kpart = ws; ws += 2 * TD;                   // max(16*DB, 2*TD) = 4.19M
  ushort_t* hnb  = (ushort_t*)ws;
  ushort_t* xcb  = hnb + TD;
  ushort_t* ybf  = xcb + TI;
  ushort_t* dbcb = ybf + TI;
  ushort_t* inwb = dbcb + DB;
  ushort_t* xpwb = inwb + INW;
  ushort_t* dtwb = xpwb + XPW;
  ushort_t* ouwb = dtwb + DTW;

  const float* hcur = h_in;
  for (int i = 0; i < 2; ++i) {
    // weight conversions (f32 -> bf16) for this layer
    f2bf_kernel<<<(INW / 4 + 255) / 256, 256, 0, stream>>>(
        in_w + (size_t)i * INW, inwb, (int)(INW / 4));
    f2bf_kernel<<<(XPW / 4 + 255) / 256, 256, 0, stream>>>(
        xp_w + (size_t)i * XPW, xpwb, (int)(XPW / 4));
    f2bf_kernel<<<(DTW / 4 + 255) / 256, 256, 0, stream>>>(
        dt_w + (size_t)i * DTW, dtwb, (int)(DTW / 4));
    f2bf_kernel<<<(OUW / 4 + 255) / 256, 256, 0, stream>>>(
        out_w + (size_t)i * OUW, ouwb, (int)(OUW / 4));

    addrms_kernel<<<SEQ, 256, 0, stream>>>(hcur, i == 0 ? nullptr : res,
                                           norm_w + (size_t)i * D_MODEL, res,
                                           nullptr, hnb);
    // in_proj: [2048 x 1024] x [4096 x 1024]^T -> xz [2048 x 4096]
    gemm_bt<1, false><<<dim3(32, 16, 1), 256, 0, stream>>>(
        hnb, inwb, xz, SEQ, 2 * D_INNER, D_MODEL, D_MODEL, D_MODEL, 2 * D_INNER);
    conv_silu_kernel<<<TI / 256, 256, 0, stream>>>(
        xz, conv_w + (size_t)i * D_INNER * 4, conv_b + (size_t)i * D_INNER, xcb);
    // x_proj: [2048 x 2048] x [96 x 2048]^T, split-K=16 -> kpart
    gemm_bt<16, true><<<dim3(1, 16, 16), 256, 0, stream>>>(
        xcb, xpwb, kpart, SEQ, DPROJ, D_INNER, D_INNER, D_INNER, DPROJ);
    reduceN_kernel<<<(DB + 255) / 256, 256, 0, stream>>>(kpart, dbc, dbcb, (int)DB, 16);
    // dt_proj: [2048 x 96(use 64)] x [2048 x 64]^T -> dtb [2048 x 2048]
    gemm_bt<1, false><<<dim3(16, 16, 1), 256, 0, stream>>>(
        dbcb, dtwb, dtb, SEQ, D_INNER, DT_RANK, DPROJ, DT_RANK, D_INNER);
    dt_softplus_kernel<<<TI / 256, 256, 0, stream>>>(dtb, dt_b + (size_t)i * D_INNER);
    scan_passA_kernel<<<dim3(NCH, D_INNER / 256), 256, 0, stream>>>(
        dtb, xcb, dbc, A_log + (size_t)i * D_INNER * NSTATE, aprod, hend);
    scan_passB_kernel<<<(D_INNER * NSTATE) / 256, 256, 0, stream>>>(aprod, hend, hin);
    scan_passC_kernel<<<dim3(NCH, D_INNER / 256), 256, 0, stream>>>(
        dtb, xcb, dbc, A_log + (size_t)i * D_INNER * NSTATE,
        Dp + (size_t)i * D_INNER, xz, hin, ybf);
    // out_proj: [2048 x 2048] x [1024 x 2048]^T, split-K=2 -> kpart, reduce -> hbuf
    gemm_bt<2, false><<<dim3(8, 16, 2), 256, 0, stream>>>(
        ybf, ouwb, kpart, SEQ, D_MODEL, D_INNER, D_INNER, D_INNER, D_MODEL);
    reduceN_kernel<<<((int)TD + 255) / 256, 256, 0, stream>>>(
        kpart, hbuf, nullptr, (int)TD, 2);
    hcur = hbuf;
  }
  addrms_kernel<<<SEQ, 256, 0, stream>>>(hbuf, res, normf, res, out, nullptr);
}

// Round 4
// 429.590 us; speedup vs baseline: 4.5093x; 1.3164x over previous
//
#include <hip/hip_runtime.h>
#include <math.h>

#define D_MODEL 1024
#define D_INNER 2048
#define DPROJ   96      // DT_RANK + 2*D_STATE
#define DT_RANK 64
#define NSTATE  16
#define SEQ     2048
#define CL      16      // chunk length for scan
#define NCH     (SEQ/CL)
#define LOG2E   1.44269504088896340736f

typedef unsigned short ushort_t;
typedef short v8s __attribute__((ext_vector_type(8)));
typedef float v4f __attribute__((ext_vector_type(4)));
typedef __attribute__((address_space(3))) unsigned int as3_u32;
typedef __attribute__((address_space(1))) unsigned int as1_u32;

__device__ __forceinline__ float silu_f(float x) { return x / (1.f + expf(-x)); }

__device__ __forceinline__ ushort_t f2bf(float f) {
  union { float f; unsigned u; } x; x.f = f;
  unsigned r = x.u + 0x7fffu + ((x.u >> 16) & 1u);  // RNE; inputs finite
  return (ushort_t)(r >> 16);
}
__device__ __forceinline__ float bf2f(ushort_t b) {
  union { unsigned u; float f; } x; x.u = ((unsigned)b) << 16; return x.f;
}

// async global->LDS, 16B per lane; lds dest = wave-uniform base + lane*16
__device__ __forceinline__ void gl_lds16(const ushort_t* g, ushort_t* l) {
  __builtin_amdgcn_global_load_lds((const as1_u32*)g, (as3_u32*)l, 16, 0, 0);
}

// res = a (+ b); xn = rmsnorm(res)*w written as bf16
__global__ __launch_bounds__(256) void addrms_kernel(
    const float* __restrict__ a, const float* __restrict__ b,
    const float* __restrict__ w, float* __restrict__ res_out,
    float* __restrict__ xnf, ushort_t* __restrict__ xnb) {
  int t = blockIdx.x;
  int tid = threadIdx.x;
  float v[4];
  float ss = 0.f;
#pragma unroll
  for (int j = 0; j < 4; ++j) {
    int dcol = tid + j * 256;
    float x = a[(size_t)t * D_MODEL + dcol];
    if (b) x += b[(size_t)t * D_MODEL + dcol];
    v[j] = x;
    ss += x * x;
  }
#pragma unroll
  for (int off = 32; off > 0; off >>= 1) ss += __shfl_down(ss, off);
  __shared__ float red[4];
  __shared__ float rmsv;
  int wid = tid >> 6, lane = tid & 63;
  if (lane == 0) red[wid] = ss;
  __syncthreads();
  if (tid == 0) {
    float s = red[0] + red[1] + red[2] + red[3];
    rmsv = rsqrtf(s / (float)D_MODEL + 1e-5f);
  }
  __syncthreads();
  float r = rmsv;
#pragma unroll
  for (int j = 0; j < 4; ++j) {
    int dcol = tid + j * 256;
    res_out[(size_t)t * D_MODEL + dcol] = v[j];
    float xn = v[j] * r * w[dcol];
    if (xnf) xnf[(size_t)t * D_MODEL + dcol] = xn;
    if (xnb) xnb[(size_t)t * D_MODEL + dcol] = f2bf(xn);
  }
}

__global__ __launch_bounds__(256) void f2bf_kernel(
    const float* __restrict__ in, ushort_t* __restrict__ out, int n4) {
  int i = blockIdx.x * 256 + threadIdx.x;
  if (i >= n4) return;
  float4 v = ((const float4*)in)[i];
  ushort4 o;
  o.x = f2bf(v.x); o.y = f2bf(v.y); o.z = f2bf(v.z); o.w = f2bf(v.w);
  ((ushort4*)out)[i] = o;
}

// ------------- bf16 MFMA GEMM (NT): C[m,n] = sum_k A[m,k]*B[n,k] -------------
// m97 structure: 128x128 tile, BK=32, linear LDS [128][32] bf16, global_load_lds
// width16 staging, 4 waves (2x2), 4x4 frags of 16x16x32 each.
// SPLITK>1: blockIdx.z takes K-chunk, C offset z*M*ldc (deterministic partials).
// EPI==1: C = softplus(acc + bias[col])
template <int SPLITK, bool CLAMPN, int EPI>
__global__ __launch_bounds__(256) void gemm_bt(
    const ushort_t* __restrict__ A, const ushort_t* __restrict__ B,
    float* __restrict__ C, const float* __restrict__ bias,
    int M, int N, int K, int lda, int ldb, int ldc) {
  __shared__ ushort_t As[128 * 32];
  __shared__ ushort_t Bs[128 * 32];
  int tid = threadIdx.x;
  int bm = blockIdx.y * 128;
  int bn = blockIdx.x * 128;
  int kchunk = K / SPLITK;
  int k0 = blockIdx.z * kchunk;
  if (SPLITK > 1) C += (size_t)blockIdx.z * (size_t)M * (size_t)ldc;

  int lane = tid & 63, wid = tid >> 6;
  int wr = wid >> 1, wc = wid & 1;
  int lr = lane & 15;
  int ko = (lane >> 4) * 8;

  int rs0 = wid * 16 + (lane >> 2);
  int segc = (lane & 3) * 8;

  v4f acc[4][4] = {};

  for (int kt = k0; kt < k0 + kchunk; kt += 32) {
#pragma unroll
    for (int s = 0; s < 2; ++s) {
      int r = s * 64 + rs0;
      int cc = kt + segc;
      gl_lds16(A + (size_t)(bm + r) * lda + cc, &As[s * 2048 + wid * 512]);
      int bc = bn + r;
      if (CLAMPN) bc = min(bc, N - 1);   // stay in-bounds; junk cols never stored
      gl_lds16(B + (size_t)bc * ldb + cc, &Bs[s * 2048 + wid * 512]);
    }
    __syncthreads();
    v8s a[4], b[4];
#pragma unroll
    for (int m = 0; m < 4; ++m)
      a[m] = *(const v8s*)&As[(wr * 64 + m * 16 + lr) * 32 + ko];
#pragma unroll
    for (int n = 0; n < 4; ++n)
      b[n] = *(const v8s*)&Bs[(wc * 64 + n * 16 + lr) * 32 + ko];
#pragma unroll
    for (int m = 0; m < 4; ++m)
#pragma unroll
      for (int n = 0; n < 4; ++n)
        acc[m][n] = __builtin_amdgcn_mfma_f32_16x16x32_bf16(a[m], b[n], acc[m][n], 0, 0, 0);
    __syncthreads();
  }

#pragma unroll
  for (int m = 0; m < 4; ++m) {
#pragma unroll
    for (int n = 0; n < 4; ++n) {
      int gc = bn + wc * 64 + n * 16 + lr;
      if (gc >= N) continue;
      int gr0 = bm + wr * 64 + m * 16 + (lane >> 4) * 4;
      float bv = (EPI == 1) ? bias[gc] : 0.f;
#pragma unroll
      for (int j = 0; j < 4; ++j) {
        float val = acc[m][n][j];
        if (EPI == 1) {
          float x = val + bv;
          val = fmaxf(x, 0.f) + log1pf(expf(-fabsf(x)));
        }
        C[(size_t)(gr0 + j) * ldc + gc] = val;
      }
    }
  }
}

// out[idx] = sum_p part[idx + p*sz]; optional bf16 mirror
__global__ __launch_bounds__(256) void reduceN_kernel(
    const float* __restrict__ part, float* __restrict__ out,
    ushort_t* __restrict__ outb, int sz, int nparts) {
  int idx = blockIdx.x * 256 + threadIdx.x;
  if (idx >= sz) return;
  float s = 0.f;
  for (int p = 0; p < nparts; ++p) s += part[idx + (size_t)p * sz];
  out[idx] = s;
  if (outb) outb[idx] = f2bf(s);
}

// depthwise causal conv (k=4) + silu -> bf16
__global__ __launch_bounds__(256) void conv_silu_kernel(
    const float* __restrict__ xz, const float* __restrict__ cw,
    const float* __restrict__ cb, ushort_t* __restrict__ xcb) {
  int idx = blockIdx.x * 256 + threadIdx.x;
  int t = idx >> 11;
  int c = idx & 2047;
  float acc = cb[c];
  float w0 = cw[c * 4 + 0], w1 = cw[c * 4 + 1], w2 = cw[c * 4 + 2], w3 = cw[c * 4 + 3];
  if (t >= 3) acc += xz[(size_t)(t - 3) * 4096 + c] * w0;
  if (t >= 2) acc += xz[(size_t)(t - 2) * 4096 + c] * w1;
  if (t >= 1) acc += xz[(size_t)(t - 1) * 4096 + c] * w2;
  acc += xz[(size_t)t * 4096 + c] * w3;
  xcb[idx] = f2bf(silu_f(acc));
}

// Pass A: per-chunk cumulative dA product + local end state (h0 = 0)
__global__ __launch_bounds__(256) void scan_passA_kernel(
    const float* __restrict__ dtb, const ushort_t* __restrict__ xcb,
    const float* __restrict__ dbc, const float* __restrict__ A_log,
    float* __restrict__ aprod, float* __restrict__ hend) {
  int c = blockIdx.x;
  int d = blockIdx.y * 256 + threadIdx.x;
  float Av[NSTATE], h[NSTATE], ap[NSTATE];
#pragma unroll
  for (int n = 0; n < NSTATE; ++n) {
    Av[n] = -expf(A_log[(size_t)d * NSTATE + n]) * LOG2E;
    h[n] = 0.f;
    ap[n] = 1.f;
  }
  int t0 = c * CL;
#pragma unroll 4
  for (int tt = 0; tt < CL; ++tt) {
    int t = t0 + tt;
    float dtv = dtb[(size_t)t * D_INNER + d];
    float uv  = bf2f(xcb[(size_t)t * D_INNER + d]);
    float du = dtv * uv;
    const float* Brow = &dbc[(size_t)t * DPROJ + DT_RANK];
#pragma unroll
    for (int n = 0; n < NSTATE; ++n) {
      float dA = exp2f(dtv * Av[n]);
      h[n] = fmaf(dA, h[n], du * Brow[n]);
      ap[n] *= dA;
    }
  }
  size_t base = ((size_t)c * D_INNER + d) * NSTATE;
#pragma unroll
  for (int n = 0; n < NSTATE; ++n) {
    aprod[base + n] = ap[n];
    hend[base + n] = h[n];
  }
}

// Pass B: sequential carry across chunks; rewrites hend in place with the
// INCOMING state for each chunk (hin).
__global__ __launch_bounds__(256) void scan_passB_kernel(
    const float* __restrict__ aprod, float* __restrict__ hend_hin) {
  size_t idx = (size_t)blockIdx.x * 256 + threadIdx.x;
  const size_t stride = (size_t)D_INNER * NSTATE;
  float h = 0.f;
  for (int c = 0; c < NCH; ++c) {
    float a = aprod[c * stride + idx];
    float e = hend_hin[c * stride + idx];
    hend_hin[c * stride + idx] = h;
    h = fmaf(a, h, e);
  }
}

// Pass C: rescan from hin; y = (scan + u*D) * silu(z), written as bf16
__global__ __launch_bounds__(256) void scan_passC_kernel(
    const float* __restrict__ dtb, const ushort_t* __restrict__ xcb,
    const float* __restrict__ dbc, const float* __restrict__ A_log,
    const float* __restrict__ Dp, const float* __restrict__ xz,
    const float* __restrict__ hin, ushort_t* __restrict__ yb) {
  int c = blockIdx.x;
  int d = blockIdx.y * 256 + threadIdx.x;
  float Av[NSTATE], h[NSTATE];
  size_t base = ((size_t)c * D_INNER + d) * NSTATE;
#pragma unroll
  for (int n = 0; n < NSTATE; ++n) {
    Av[n] = -expf(A_log[(size_t)d * NSTATE + n]) * LOG2E;
    h[n] = hin[base + n];
  }
  float Dv = Dp[d];
  int t0 = c * CL;
#pragma unroll 4
  for (int tt = 0; tt < CL; ++tt) {
    int t = t0 + tt;
    float dtv = dtb[(size_t)t * D_INNER + d];
    float uv  = bf2f(xcb[(size_t)t * D_INNER + d]);
    float du = dtv * uv;
    const float* Brow = &dbc[(size_t)t * DPROJ + DT_RANK];
    const float* Crow = &dbc[(size_t)t * DPROJ + DT_RANK + NSTATE];
    float yv = 0.f;
#pragma unroll
    for (int n = 0; n < NSTATE; ++n) {
      float dA = exp2f(dtv * Av[n]);
      h[n] = fmaf(dA, h[n], du * Brow[n]);
      yv = fmaf(h[n], Crow[n], yv);
    }
    float zv = xz[(size_t)t * (2 * D_INNER) + D_INNER + d];
    yb[(size_t)t * D_INNER + d] = f2bf((yv + uv * Dv) * silu_f(zv));
  }
}

extern "C" void kernel_launch(void* const* d_in, const int* in_sizes, int n_in,
                              void* d_out, int out_size, void* d_ws, size_t ws_size,
                              hipStream_t stream) {
  const float* h_in   = (const float*)d_in[0];
  const float* norm_w = (const float*)d_in[1];
  const float* in_w   = (const float*)d_in[2];
  const float* conv_w = (const float*)d_in[3];
  const float* conv_b = (const float*)d_in[4];
  const float* xp_w   = (const float*)d_in[5];
  const float* dt_w   = (const float*)d_in[6];
  const float* dt_b   = (const float*)d_in[7];
  const float* A_log  = (const float*)d_in[8];
  const float* Dp     = (const float*)d_in[9];
  const float* out_w  = (const float*)d_in[10];
  const float* normf  = (const float*)d_in[11];
  float* out = (float*)d_out;

  float* ws = (float*)d_ws;
  const size_t TD = (size_t)SEQ * D_MODEL;            // 2M
  const size_t TI = (size_t)SEQ * D_INNER;            // 4M
  const size_t ST = (size_t)NCH * D_INNER * NSTATE;   // 4.19M (CL=16)
  const size_t DB = (size_t)SEQ * DPROJ;              // 196608
  const size_t INW = (size_t)2 * D_INNER * D_MODEL;   // 4.19M
  const size_t XPW = (size_t)DPROJ * D_INNER;         // 196608
  const size_t DTW = (size_t)D_INNER * DT_RANK;       // 131072
  const size_t OUW = (size_t)D_MODEL * D_INNER;       // 2.10M

  float* res   = ws; ws += TD;
  float* xz    = ws; ws += 2 * TI;
  float* dbc   = ws; ws += DB;
  float* dtb   = ws; ws += TI;
  float* hbuf  = ws; ws += TD;
  float* aprod = ws; ws += ST;   // also aliased as kpart (disjoint lifetimes)
  float* hend  = ws; ws += ST;   // doubles as hin after passB
  float* kpart = aprod;
  ushort_t* hnb  = (ushort_t*)ws;
  ushort_t* xcb  = hnb + TD;
  ushort_t* ybf  = xcb + TI;
  ushort_t* dbcb = ybf + TI;
  ushort_t* inwb = dbcb + DB;
  ushort_t* xpwb = inwb + INW;
  ushort_t* dtwb = xpwb + XPW;
  ushort_t* ouwb = dtwb + DTW;

  const float* hcur = h_in;
  for (int i = 0; i < 2; ++i) {
    f2bf_kernel<<<(INW / 4 + 255) / 256, 256, 0, stream>>>(
        in_w + (size_t)i * INW, inwb, (int)(INW / 4));
    f2bf_kernel<<<(XPW / 4 + 255) / 256, 256, 0, stream>>>(
        xp_w + (size_t)i * XPW, xpwb, (int)(XPW / 4));
    f2bf_kernel<<<(DTW / 4 + 255) / 256, 256, 0, stream>>>(
        dt_w + (size_t)i * DTW, dtwb, (int)(DTW / 4));
    f2bf_kernel<<<(OUW / 4 + 255) / 256, 256, 0, stream>>>(
        out_w + (size_t)i * OUW, ouwb, (int)(OUW / 4));

    addrms_kernel<<<SEQ, 256, 0, stream>>>(hcur, i == 0 ? nullptr : res,
                                           norm_w + (size_t)i * D_MODEL, res,
                                           nullptr, hnb);
    // in_proj: [2048 x 1024] x [4096 x 1024]^T -> xz [2048 x 4096]
    gemm_bt<1, false, 0><<<dim3(32, 16, 1), 256, 0, stream>>>(
        hnb, inwb, xz, nullptr, SEQ, 2 * D_INNER, D_MODEL, D_MODEL, D_MODEL, 2 * D_INNER);
    conv_silu_kernel<<<TI / 256, 256, 0, stream>>>(
        xz, conv_w + (size_t)i * D_INNER * 4, conv_b + (size_t)i * D_INNER, xcb);
    // x_proj: [2048 x 2048] x [96 x 2048]^T, split-K=16 -> kpart
    gemm_bt<16, true, 0><<<dim3(1, 16, 16), 256, 0, stream>>>(
        xcb, xpwb, kpart, nullptr, SEQ, DPROJ, D_INNER, D_INNER, D_INNER, DPROJ);
    reduceN_kernel<<<(DB + 255) / 256, 256, 0, stream>>>(kpart, dbc, dbcb, (int)DB, 16);
    // dt_proj: [2048 x 96(use 64)] x [2048 x 64]^T -> softplus(.+b) -> dtb
    gemm_bt<1, false, 1><<<dim3(16, 16, 1), 256, 0, stream>>>(
        dbcb, dtwb, dtb, dt_b + (size_t)i * D_INNER,
        SEQ, D_INNER, DT_RANK, DPROJ, DT_RANK, D_INNER);
    scan_passA_kernel<<<dim3(NCH, D_INNER / 256), 256, 0, stream>>>(
        dtb, xcb, dbc, A_log + (size_t)i * D_INNER * NSTATE, aprod, hend);
    scan_passB_kernel<<<(D_INNER * NSTATE) / 256, 256, 0, stream>>>(aprod, hend);
    scan_passC_kernel<<<dim3(NCH, D_INNER / 256), 256, 0, stream>>>(
        dtb, xcb, dbc, A_log + (size_t)i * D_INNER * NSTATE,
        Dp + (size_t)i * D_INNER, xz, hend, ybf);
    // out_proj: [2048 x 2048] x [1024 x 2048]^T, split-K=2 -> kpart, reduce -> hbuf
    gemm_bt<2, false, 0><<<dim3(8, 16, 2), 256, 0, stream>>>(
        ybf, ouwb, kpart, nullptr, SEQ, D_MODEL, D_INNER, D_INNER, D_INNER, D_MODEL);
    reduceN_kernel<<<((int)TD + 255) / 256, 256, 0, stream>>>(
        kpart, hbuf, nullptr, (int)TD, 2);
    hcur = hbuf;
  }
  addrms_kernel<<<SEQ, 256, 0, stream>>>(hbuf, res, normf, res, out, nullptr);
}